// Round 1
// baseline (782.811 us; speedup 1.0000x reference)
//
#include <hip/hip_runtime.h>

// Haar downsample: x (8,64,512,512) f32 -> out (8,192,256,256) f32.
// o0=(a-b-c+d)/2, o1=(a-b+c-d)/2, o2=(a+b-c-d)/2 where
// a=x[2h,2w], b=x[2h,2w+1], c=x[2h+1,2w], d=x[2h+1,2w+1].
// Memory-bound: 512 MiB in + 384 MiB out => ~142 us roofline @ 6.3 TB/s.

#define BC_TOTAL 512       // B*C = 8*64
#define H 512
#define W 512
#define H2 256
#define W2 256
#define IN_PLANE (H * W)        // 262144
#define OUT_PLANE (H2 * W2)     // 65536

// One thread: 4 output columns => 8 input columns across 2 rows.
// Loads: 4x float4 (16B/lane, coalesced). Stores: 3x float4.
__global__ __launch_bounds__(256) void haar_down_kernel(
    const float* __restrict__ in, float* __restrict__ out) {
    const int idx = blockIdx.x * blockDim.x + threadIdx.x;
    const int w8 = idx & 63;          // 64 groups of 8 input cols per row
    const int h2 = (idx >> 6) & 255;  // 256 output rows
    const int bc = idx >> 14;         // 512 (b,c) planes

    const float* ib = in + (size_t)bc * IN_PLANE + ((size_t)(h2 << 1)) * W + (w8 << 3);
    const float4 r0a = *reinterpret_cast<const float4*>(ib);
    const float4 r0b = *reinterpret_cast<const float4*>(ib + 4);
    const float4 r1a = *reinterpret_cast<const float4*>(ib + W);
    const float4 r1b = *reinterpret_cast<const float4*>(ib + W + 4);

    // r0: a0 b0 a1 b1 | a2 b2 a3 b3 ; r1: c0 d0 c1 d1 | c2 d2 c3 d3
    float4 o0, o1, o2;
    {
        const float a = r0a.x, b = r0a.y, c = r1a.x, d = r1a.y;
        o0.x = (a - b - c + d) * 0.5f;
        o1.x = (a - b + c - d) * 0.5f;
        o2.x = (a + b - c - d) * 0.5f;
    }
    {
        const float a = r0a.z, b = r0a.w, c = r1a.z, d = r1a.w;
        o0.y = (a - b - c + d) * 0.5f;
        o1.y = (a - b + c - d) * 0.5f;
        o2.y = (a + b - c - d) * 0.5f;
    }
    {
        const float a = r0b.x, b = r0b.y, c = r1b.x, d = r1b.y;
        o0.z = (a - b - c + d) * 0.5f;
        o1.z = (a - b + c - d) * 0.5f;
        o2.z = (a + b - c - d) * 0.5f;
    }
    {
        const float a = r0b.z, b = r0b.w, c = r1b.z, d = r1b.w;
        o0.w = (a - b - c + d) * 0.5f;
        o1.w = (a - b + c - d) * 0.5f;
        o2.w = (a + b - c - d) * 0.5f;
    }

    // out[b][c][k][h2][w2]: plane stride OUT_PLANE, (b,c) stride 3*OUT_PLANE
    float* ob = out + (size_t)bc * (3 * OUT_PLANE) + ((size_t)h2 << 8) + (w8 << 2);
    *reinterpret_cast<float4*>(ob) = o0;
    *reinterpret_cast<float4*>(ob + OUT_PLANE) = o1;
    *reinterpret_cast<float4*>(ob + 2 * OUT_PLANE) = o2;
}

extern "C" void kernel_launch(void* const* d_in, const int* in_sizes, int n_in,
                              void* d_out, int out_size, void* d_ws, size_t ws_size,
                              hipStream_t stream) {
    const float* x = (const float*)d_in[0];
    float* out = (float*)d_out;
    // total threads = 512 * 256 * 64 = 8,388,608 -> 32768 blocks of 256
    const int total = BC_TOTAL * H2 * (W2 / 4);
    haar_down_kernel<<<total / 256, 256, 0, stream>>>(x, out);
}